// Round 12
// baseline (279.179 us; speedup 1.0000x reference)
//
#include <hip/hip_runtime.h>
#include <hip/hip_bf16.h>
#include <stdint.h>

// Problem: B=4, N=2048, D=1024, H=16, HD=64, SCALE=1/8. Inputs fp32 (detected
// on-device), compute bf16 MFMA, output dtype follows flag.
// Round 20:
//   * flash v5b + T5 s_setprio(1) around both MFMA clusters (S^T and PV).
//     flash has 4 independent blocks/CU at different kb-phases (the attn-like
//     regime where m191 measured +4-7%); biases CU scheduler to keep the
//     matrix pipe fed while other blocks' waves run exp/staging VALU.
//   * qkv_gemm, proj_gemm: BK=64 + T2 chunk-XOR swizzle (R18/R19, best
//     measured total 261.3).

typedef __attribute__((ext_vector_type(8))) short short8;    // 8 bf16
typedef __attribute__((ext_vector_type(4))) short short4v;   // 4 bf16
typedef __attribute__((ext_vector_type(4))) float float4v;   // 16x16 C/D
typedef __attribute__((ext_vector_type(16))) float float16v; // 32x32 C/D

#define MFMA16(a, b, c) __builtin_amdgcn_mfma_f32_16x16x32_bf16((a), (b), (c), 0, 0, 0)
#define MFMA32(a, b, c) __builtin_amdgcn_mfma_f32_32x32x16_bf16((a), (b), (c), 0, 0, 0)

static __device__ __forceinline__ unsigned short f2bf(float f) {
  union { float f; unsigned u; } v; v.f = f;
  unsigned r = v.u + 0x7fffu + ((v.u >> 16) & 1u);   // RNE
  return (unsigned short)(r >> 16);
}
static __device__ __forceinline__ float bf2f(unsigned short u) {
  union { unsigned u; float f; } v; v.u = ((unsigned)u) << 16;
  return v.f;
}
static __device__ __forceinline__ unsigned pkbf(float a, float b) {
  union { __hip_bfloat162 v; unsigned u; } c;
  c.v = __float22bfloat162_rn(make_float2(a, b));    // v_cvt_pk_bf16_f32
  return c.u;  // lo = a, hi = b
}
static __device__ __forceinline__ float ex2(float x) {
#if __has_builtin(__builtin_amdgcn_exp2f)
  return __builtin_amdgcn_exp2f(x);                  // raw v_exp_f32 (2^x)
#else
  return exp2f(x);
#endif
}
static __device__ __forceinline__ float4v fzero() {
  float4v z; z[0] = 0.f; z[1] = 0.f; z[2] = 0.f; z[3] = 0.f; return z;
}
static __device__ __forceinline__ float16v fzero16() {
  float16v z;
#pragma unroll
  for (int i = 0; i < 16; ++i) z[i] = 0.f;
  return z;
}
// v_permlane32_swap_b32 a, b:
//   a <- (a_lo, b_lo)  [b's lower half into a's upper half]
//   b <- (a_hi, b_hi)  [a's upper half into b's lower half]
static __device__ __forceinline__ void pl32swap(unsigned& a, unsigned& b) {
  asm volatile("v_permlane32_swap_b32 %0, %1" : "+v"(a), "+v"(b));
}
// async global->LDS, 16B per lane; LDS dest is wave-uniform base + lane*16
static __device__ __forceinline__ void load_lds16(const void* g, void* l) {
  typedef const __attribute__((address_space(1))) void* gp_t;
  typedef __attribute__((address_space(3))) void* lp_t;
  __builtin_amdgcn_global_load_lds((gp_t)(uintptr_t)g, (lp_t)(uint32_t)(uintptr_t)l, 16, 0, 0);
}

// ---------------------------------------------------------------------------
__global__ void detect_dtype(const unsigned short* __restrict__ x, int* flag) {
  __shared__ int cnt;
  if (threadIdx.x == 0) cnt = 0;
  __syncthreads();
  int c = 0;
  for (int i = threadIdx.x; i < 4096; i += 256) {
    const unsigned v = x[i] & 0x7FFFu;
    if ((v >> 7) >= 134u) ++c;   // exponent >= 134 -> |value| >= 128
  }
  atomicAdd(&cnt, c);
  __syncthreads();
  if (threadIdx.x == 0) *flag = (cnt > 64) ? 1 : 0;
}

// ---------------------------------------------------------------------------
// All 4 input tensors converted (or copied) in one launch; 8 elems/thread.
// ---------------------------------------------------------------------------
static __device__ __forceinline__ void cv8(const void* src, unsigned short* dst,
                                           int i, int fl) {
  if (fl) {
    const float4v a = *(const float4v*)((const float*)src + i);
    const float4v b = *(const float4v*)((const float*)src + i + 4);
    short8 o;
    o[0] = (short)f2bf(a[0]); o[1] = (short)f2bf(a[1]);
    o[2] = (short)f2bf(a[2]); o[3] = (short)f2bf(a[3]);
    o[4] = (short)f2bf(b[0]); o[5] = (short)f2bf(b[1]);
    o[6] = (short)f2bf(b[2]); o[7] = (short)f2bf(b[3]);
    *(short8*)(dst + i) = o;
  } else {
    *(short8*)(dst + i) = *(const short8*)((const unsigned short*)src + i);
  }
}
__global__ __launch_bounds__(256) void convert_all(
    const void* __restrict__ s0, const void* __restrict__ s1,
    const void* __restrict__ s2, const void* __restrict__ s3,
    unsigned short* __restrict__ d0, unsigned short* __restrict__ d1,
    unsigned short* __restrict__ d2, unsigned short* __restrict__ d3,
    const int* __restrict__ flag) {
  const int t = blockIdx.x * 256 + threadIdx.x;
  const int fl = *flag;
  if (t < 1048576)       cv8(s0, d0, t * 8, fl);
  else if (t < 1441792)  cv8(s1, d1, (t - 1048576) * 8, fl);
  else if (t < 1572864)  cv8(s2, d2, (t - 1441792) * 8, fl);
  else if (t < 1572992)  cv8(s3, d3, (t - 1572864) * 8, fl);
}

// ---------------------------------------------------------------------------
// GEMM1: qkv[m,e] = sum_k X[m,k]*Wqkv[e,k];  M=8192, E=3072, K=1024
// 128x128 tile, BK=64 (16 iters), T3-min dbuf, T2 chunk-XOR swizzle:
// LDS[row][c] holds G[row][c^(row&7)] (16B chunks; row stride 128B).
// Store side: pre-swizzled global source, linear gload_lds dest (rule #21).
// Read side: chunk (ks*4+quad)^(l16&7). Q epilogue pre-scales by
// SCALE*log2(e) so flash softmax can use 2^x.
// ---------------------------------------------------------------------------
__global__ __launch_bounds__(256) void qkv_gemm(
    const unsigned short* __restrict__ X, const unsigned short* __restrict__ W,
    unsigned short* __restrict__ Qo, unsigned short* __restrict__ Ko,
    unsigned short* __restrict__ Vt) {
  __shared__ __attribute__((aligned(16))) unsigned short lA[2][128 * 64];
  __shared__ __attribute__((aligned(16))) unsigned short lB[2][128 * 64];
  const int tid = threadIdx.x;
  const int wave = tid >> 6, lane = tid & 63, quad = lane >> 4, l16 = lane & 15;
  const int wm = wave >> 1, wn = wave & 1;
  const int m0 = blockIdx.x * 128, n0 = blockIdx.y * 128;

  float4v acc[4][4];
  for (int i = 0; i < 4; ++i) for (int j = 0; j < 4; ++j) acc[i][j] = fzero();

  // staging: 4 rounds x 2 matrices; round r covers f = r*256+tid,
  // row = f>>3 (32 rows/round), chunk = f&7; source chunk pre-swizzled.
  int srow[4], scol[4];
#pragma unroll
  for (int r = 0; r < 4; ++r) {
    const int f = r * 256 + tid;
    srow[r] = f >> 3;
    scol[r] = ((f & 7) ^ (srow[r] & 7)) * 8;   // elem offset of 16B chunk
  }
  const int lsw = l16 & 7;                      // read-side row swizzle

#define QKV_STAGE(buf, k0)                                                    \
  {                                                                           \
    _Pragma("unroll")                                                         \
    for (int r = 0; r < 4; ++r) {                                             \
      const int dof = (r * 256 + wave * 64) * 8;                              \
      load_lds16(X + (size_t)(m0 + srow[r]) * 1024 + (k0) + scol[r],          \
                 lA[buf] + dof);                                              \
      load_lds16(W + (size_t)(n0 + srow[r]) * 1024 + (k0) + scol[r],          \
                 lB[buf] + dof);                                              \
    }                                                                         \
  }

  QKV_STAGE(0, 0);
  __syncthreads();                // drains prologue loads
  int cur = 0;
  for (int k0 = 0; k0 < 1024; k0 += 64) {
    if (k0 < 960) { QKV_STAGE(cur ^ 1, k0 + 64); }   // next tile in flight
#pragma unroll
    for (int ks = 0; ks < 2; ++ks) {
      short8 af[4], bfr[4];
#pragma unroll
      for (int t = 0; t < 4; ++t) {
        const int rowA = wm * 64 + t * 16 + l16;
        const int rowB = wn * 64 + t * 16 + l16;
        const int ch = ((ks * 4 + quad) ^ lsw) * 8;
        af[t]  = *(const short8*)(lA[cur] + rowA * 64 + ch);
        bfr[t] = *(const short8*)(lB[cur] + rowB * 64 + ch);
      }
#pragma unroll
      for (int mt = 0; mt < 4; ++mt)
#pragma unroll
        for (int nt = 0; nt < 4; ++nt)
          acc[mt][nt] = MFMA16(af[mt], bfr[nt], acc[mt][nt]);
    }
    __syncthreads();              // drains next-tile loads (post-compute)
    cur ^= 1;
  }
#undef QKV_STAGE

  // 0.125 * log2(e) — softmax exponent base folded into Q
  const float QSCALE = 0.18033688011112042f;
  for (int mt = 0; mt < 4; ++mt) {
    const int mbase = m0 + wm * 64 + mt * 16 + quad * 4;
    const int b = mbase >> 11;
    const int nrow = mbase & 2047;
    for (int nt = 0; nt < 4; ++nt) {
      const int e = n0 + wn * 64 + nt * 16 + l16;
      const int c = e >> 10, h = (e >> 6) & 15, hd = e & 63;
      const int bh = b * 16 + h;
      if (c == 0) {        // Q, pre-scaled by 1/8 * log2(e)
        for (int r = 0; r < 4; ++r)
          Qo[((size_t)bh * 2048 + nrow + r) * 64 + hd] = f2bf(acc[mt][nt][r] * QSCALE);
      } else if (c == 1) { // K
        for (int r = 0; r < 4; ++r)
          Ko[((size_t)bh * 2048 + nrow + r) * 64 + hd] = f2bf(acc[mt][nt][r]);
      } else {             // V transposed: Vt[bh][hd][n]
        short4v pk;
        for (int r = 0; r < 4; ++r) pk[r] = (short)f2bf(acc[mt][nt][r]);
        *(short4v*)(Vt + ((size_t)bh * 64 + hd) * 2048 + nrow) = pk;
      }
    }
  }
}

// ---------------------------------------------------------------------------
// Flash attention v5c: v5b + T5 setprio around MFMA clusters.
// block = 128 q x one (b,h); 4 waves x 32 queries each. 32x32x16 MFMA for
// S^T and PV. Double-buffered K/V LDS, T14 async-stage.
// S^T C-regs: query=l31, key=(reg&3)+8*(reg>>2)+4*hi.
// PV B-frag (element i = key 8*hi+i) built via cvt_pk + permlane32_swap.
// ---------------------------------------------------------------------------
__global__ __launch_bounds__(256, 4) void flash_attn(
    const unsigned short* __restrict__ Q, const unsigned short* __restrict__ K,
    const unsigned short* __restrict__ Vt, unsigned short* __restrict__ AO) {
  __shared__ __attribute__((aligned(16))) unsigned short lK[2][64 * 72];   // (key, hd)
  __shared__ __attribute__((aligned(16))) unsigned short lV[2][64 * 72];   // (hd, key)
  const int tid = threadIdx.x;
  const int wave = tid >> 6, lane = tid & 63;
  const int l31 = lane & 31, hi = lane >> 5;
  const int qt = blockIdx.x, bh = blockIdx.y;
  const int b = bh >> 4, h = bh & 15;
  const size_t base = (size_t)bh * 2048 * 64;
  const unsigned short* Qp = Q + base;
  const unsigned short* Kp = K + base;
  const unsigned short* Vp = Vt + base;
  const int q0 = qt * 128;

  // wave owns queries qa..qa (32 of them via l31)
  const int qa = q0 + wave * 32 + l31;
  short8 qf[4];
#pragma unroll
  for (int j = 0; j < 4; ++j)
    qf[j] = *(const short8*)(Qp + (size_t)qa * 64 + j * 16 + hi * 8);

  // O^T accumulators, 2 hd-tiles of 32: col=query=l31, row=hd mapping
  float16v oacc0 = fzero16(), oacc1 = fzero16();
  float lsum = 0.f;   // per-lane partial row sum for query l31 (half keys)

  const int f0 = tid, f1 = 256 + tid;
  const int sk0 = (f0 >> 3) * 72 + (f0 & 7) * 8;   // padded LDS elem offset
  const int sk1 = (f1 >> 3) * 72 + (f1 & 7) * 8;

  // prologue: tile 0 into staging registers
  short8 kv0 = *(const short8*)(Kp + f0 * 8);
  short8 kv1 = *(const short8*)(Kp + f1 * 8);
  short8 vv0 = *(const short8*)(Vp + (size_t)(f0 >> 3) * 2048 + (f0 & 7) * 8);
  short8 vv1 = *(const short8*)(Vp + (size_t)(f1 >> 3) * 2048 + (f1 & 7) * 8);

  for (int kb = 0; kb < 32; ++kb) {
    unsigned short* const Kb = lK[kb & 1];
    unsigned short* const Vb = lV[kb & 1];
    // write staged tile (auto vmcnt wait lands here — loads had a full
    // compute phase to return)
    *(short8*)(Kb + sk0) = kv0;
    *(short8*)(Kb + sk1) = kv1;
    *(short8*)(Vb + sk0) = vv0;
    *(short8*)(Vb + sk1) = vv1;
    __syncthreads();
    // T14: issue next-tile loads AFTER the barrier so its vmcnt(0) drain
    // doesn't intercept them; latency hides under S^T/exp/PV below.
    if (kb < 31) {
      const size_t ko = (size_t)(kb + 1) * 4096;
      kv0 = *(const short8*)(Kp + ko + f0 * 8);
      kv1 = *(const short8*)(Kp + ko + f1 * 8);
      vv0 = *(const short8*)(Vp + (size_t)(f0 >> 3) * 2048 + (kb + 1) * 64 + (f0 & 7) * 8);
      vv1 = *(const short8*)(Vp + (size_t)(f1 >> 3) * 2048 + (kb + 1) * 64 + (f1 & 7) * 8);
    }

#pragma unroll
    for (int kb2 = 0; kb2 < 2; ++kb2) {
      // S^T = K Q^T (32 keys x 32 queries): A = K-frag row=key=l31,
      // k = j*16 + hi*8 + i; B = Q-frag col=query=l31, same k.
      const unsigned short* krow = Kb + (kb2 * 32 + l31) * 72 + hi * 8;
      float16v s = fzero16();
      __builtin_amdgcn_s_setprio(1);
#pragma unroll
      for (int j = 0; j < 4; ++j)
        s = MFMA32(*(const short8*)(krow + j * 16), qf[j], s);
      __builtin_amdgcn_s_setprio(0);

      // 2^s; lane holds keys (reg&3)+8*(reg>>2)+4*hi for reg 0..15
      unsigned u[8];
      float ls = 0.f;
#pragma unroll
      for (int j = 0; j < 8; ++j) {
        const float e0 = ex2(s[2 * j]);
        const float e1 = ex2(s[2 * j + 1]);
        ls += e0 + e1;
        u[j] = pkbf(e0, e1);
      }
      lsum += ls;

      // Relayout to PV B-frags (element i = key 8*hi+i):
      //   swap(u0,u2): u0 <- (u0_lo|u2_lo) = keys (0,1)|(8,9)   = w0
      //                u2 <- (u0_hi|u2_hi) = keys (4,5)|(12,13) = w2
      pl32swap(u[0], u[2]); pl32swap(u[1], u[3]);   // keys 0..15
      pl32swap(u[4], u[6]); pl32swap(u[5], u[7]);   // keys 16..31
      union { unsigned w[4]; short8 s8; } fr0, fr1;
      fr0.w[0] = u[0]; fr0.w[1] = u[1]; fr0.w[2] = u[2]; fr0.w[3] = u[3];
      fr1.w[0] = u[4]; fr1.w[1] = u[5]; fr1.w[2] = u[6]; fr1.w[3] = u[7];

      // O^T += V^T P^T: A = V^T row=hd=l31(+32), k=key=kb2*32+s*16+8*hi+i
      const unsigned short* vrow0 = Vb + l31 * 72 + kb2 * 32 + hi * 8;
      const unsigned short* vrow1 = vrow0 + 32 * 72;
      __builtin_amdgcn_s_setprio(1);
      oacc0 = MFMA32(*(const short8*)(vrow0), fr0.s8, oacc0);
      oacc1 = MFMA32(*(const short8*)(vrow1), fr0.s8, oacc1);
      oacc0 = MFMA32(*(const short8*)(vrow0 + 16), fr1.s8, oacc0);
      oacc1 = MFMA32(*(const short8*)(vrow1 + 16), fr1.s8, oacc1);
      __builtin_amdgcn_s_setprio(0);
    }
  }

  // row-sum: each lane has half the keys for query l31; combine hi-halves
  lsum += __shfl_xor(lsum, 32);
  const float inv = 1.f / lsum;

  // AO[b][query][h*64+hd]; hd = mt*32 + 8*g + 4*hi + r (regs 4g..4g+3)
  unsigned short* ao = AO + ((size_t)(b * 2048 + qa)) * 1024 + h * 64 + hi * 4;
#pragma unroll
  for (int mt = 0; mt < 2; ++mt) {
    const float16v& oc = mt ? oacc1 : oacc0;
#pragma unroll
    for (int g = 0; g < 4; ++g) {
      union { unsigned u2[2]; short4v s4; } o;
      o.u2[0] = pkbf(oc[4 * g] * inv, oc[4 * g + 1] * inv);
      o.u2[1] = pkbf(oc[4 * g + 2] * inv, oc[4 * g + 3] * inv);
      *(short4v*)(ao + mt * 32 + g * 8) = o.s4;
    }
  }
}

// ---------------------------------------------------------------------------
// GEMM2: out[m,e] = sum_k A[m,k]*Wp[e,k] + bias[e]; BK=64 + T2 swizzle
// (same structure as qkv_gemm); adaptive out dtype.
// ---------------------------------------------------------------------------
__global__ __launch_bounds__(256) void proj_gemm(
    const unsigned short* __restrict__ A, const unsigned short* __restrict__ W,
    const unsigned short* __restrict__ bias_bf, const void* __restrict__ bias_raw,
    void* __restrict__ outv, const int* __restrict__ flag) {
  __shared__ __attribute__((aligned(16))) unsigned short lA[2][128 * 64];
  __shared__ __attribute__((aligned(16))) unsigned short lB[2][128 * 64];
  const int tid = threadIdx.x;
  const int wave = tid >> 6, lane = tid & 63, quad = lane >> 4, l16 = lane & 15;
  const int wm = wave >> 1, wn = wave & 1;
  const int m0 = blockIdx.x * 128, n0 = blockIdx.y * 128;
  const int fl = *flag;

  float4v acc[4][4];
  for (int i = 0; i < 4; ++i) for (int j = 0; j < 4; ++j) acc[i][j] = fzero();

  int srow[4], scol[4];
#pragma unroll
  for (int r = 0; r < 4; ++r) {
    const int f = r * 256 + tid;
    srow[r] = f >> 3;
    scol[r] = ((f & 7) ^ (srow[r] & 7)) * 8;
  }
  const int lsw = l16 & 7;

#define PROJ_STAGE(buf, k0)                                                   \
  {                                                                           \
    _Pragma("unroll")                                                         \
    for (int r = 0; r < 4; ++r) {                                             \
      const int dof = (r * 256 + wave * 64) * 8;                              \
      load_lds16(A + (size_t)(m0 + srow[r]) * 1024 + (k0) + scol[r],          \
                 lA[buf] + dof);                                              \
      load_lds16(W + (size_t)(n0 + srow[r]) * 1024 + (k0) + scol[r],          \
                 lB[buf] + dof);                                              \
    }                                                                         \
  }

  PROJ_STAGE(0, 0);
  __syncthreads();
  int cur = 0;
  for (int k0 = 0; k0 < 1024; k0 += 64) {
    if (k0 < 960) { PROJ_STAGE(cur ^ 1, k0 + 64); }
#pragma unroll
    for (int ks = 0; ks < 2; ++ks) {
      short8 af[4], bfr[4];
#pragma unroll
      for (int t = 0; t < 4; ++t) {
        const int rowA = wm * 64 + t * 16 + l16;
        const int rowB = wn * 64 + t * 16 + l16;
        const int ch = ((ks * 4 + quad) ^ lsw) * 8;
        af[t]  = *(const short8*)(lA[cur] + rowA * 64 + ch);
        bfr[t] = *(const short8*)(lB[cur] + rowB * 64 + ch);
      }
#pragma unroll
      for (int mt = 0; mt < 4; ++mt)
#pragma unroll
        for (int nt = 0; nt < 4; ++nt)
          acc[mt][nt] = MFMA16(af[mt], bfr[nt], acc[mt][nt]);
    }
    __syncthreads();
    cur ^= 1;
  }
#undef PROJ_STAGE

  for (int mt = 0; mt < 4; ++mt) {
    const int mbase = m0 + wm * 64 + mt * 16 + quad * 4;
    for (int nt = 0; nt < 4; ++nt) {
      const int e = n0 + wn * 64 + nt * 16 + l16;
      const float bv = fl ? ((const float*)bias_raw)[e] : bf2f(bias_bf[e]);
      for (int r = 0; r < 4; ++r) {
        const float val = acc[mt][nt][r] + bv;
        const size_t idx = (size_t)(mbase + r) * 1024 + e;
        if (fl) ((float*)outv)[idx] = val;
        else    ((unsigned short*)outv)[idx] = f2bf(val);
      }
    }
  }
}

// ---------------------------------------------------------------------------
extern "C" void kernel_launch(void* const* d_in, const int* in_sizes, int n_in,
                              void* d_out, int out_size, void* d_ws, size_t ws_size,
                              hipStream_t stream) {
  const void* x_raw     = d_in[0];  // (8192,1024)
  const void* wqkv_raw  = d_in[1];  // (3072,1024)
  const void* wproj_raw = d_in[2];  // (1024,1024)
  const void* bproj_raw = d_in[3];  // (1024,)

  const size_t NE = (size_t)4 * 16 * 2048 * 64;  // 8388608
  unsigned short* ws = (unsigned short*)d_ws;
  unsigned short* Q      = ws;
  unsigned short* K      = Q + NE;
  unsigned short* Vt     = K + NE;
  unsigned short* xb     = Vt + NE;        // also AO (xb dead after qkv_gemm)
  unsigned short* AO     = xb;
  unsigned short* wqkvb  = xb + NE;
  unsigned short* wprojb = wqkvb + 3145728;
  unsigned short* bprojb = wprojb + 1048576;
  int* flag = (int*)(bprojb + 1024);

  detect_dtype<<<1, 256, 0, stream>>>((const unsigned short*)x_raw, flag);
  convert_all<<<6145, 256, 0, stream>>>(x_raw, wqkv_raw, wproj_raw, bproj_raw,
                                        xb, wqkvb, wprojb, bprojb, flag);

  qkv_gemm<<<dim3(64, 24), 256, 0, stream>>>(xb, wqkvb, Q, K, Vt);
  flash_attn<<<dim3(16, 64), 256, 0, stream>>>(Q, K, Vt, AO);
  proj_gemm<<<dim3(64, 8), 256, 0, stream>>>(AO, wprojb, bprojb, bproj_raw,
                                             d_out, flag);
}

// Round 13
// 258.129 us; speedup vs baseline: 1.0815x; 1.0815x over previous
//
#include <hip/hip_runtime.h>
#include <hip/hip_bf16.h>
#include <stdint.h>

// Problem: B=4, N=2048, D=1024, H=16, HD=64, SCALE=1/8. Inputs fp32 (detected
// on-device), compute bf16 MFMA, output dtype follows flag.
// Round 21 (FINAL config): revert R20's setprio (flash 94.0 -> 97.2, the
// m190-lockstep-null regime: boosting one block's MFMA waves starves the
// co-resident block's staging loads). This is the exact R19 configuration:
//   * flash v5b: 32x32 MFMA S^T+PV, operand swap, cvt_pk+permlane32_swap
//     P-relayout, exp2 fold, dbuf+T14. 93.7-94.0us stable, 85% issue-bound.
//   * qkv/proj GEMMs: BK=64 + T2 chunk-XOR swizzle, T3-min dbuf (the R18
//     win: halved per-iteration barrier/drain fixed cost; total 261.3 best).

typedef __attribute__((ext_vector_type(8))) short short8;    // 8 bf16
typedef __attribute__((ext_vector_type(4))) short short4v;   // 4 bf16
typedef __attribute__((ext_vector_type(4))) float float4v;   // 16x16 C/D
typedef __attribute__((ext_vector_type(16))) float float16v; // 32x32 C/D

#define MFMA16(a, b, c) __builtin_amdgcn_mfma_f32_16x16x32_bf16((a), (b), (c), 0, 0, 0)
#define MFMA32(a, b, c) __builtin_amdgcn_mfma_f32_32x32x16_bf16((a), (b), (c), 0, 0, 0)

static __device__ __forceinline__ unsigned short f2bf(float f) {
  union { float f; unsigned u; } v; v.f = f;
  unsigned r = v.u + 0x7fffu + ((v.u >> 16) & 1u);   // RNE
  return (unsigned short)(r >> 16);
}
static __device__ __forceinline__ float bf2f(unsigned short u) {
  union { unsigned u; float f; } v; v.u = ((unsigned)u) << 16;
  return v.f;
}
static __device__ __forceinline__ unsigned pkbf(float a, float b) {
  union { __hip_bfloat162 v; unsigned u; } c;
  c.v = __float22bfloat162_rn(make_float2(a, b));    // v_cvt_pk_bf16_f32
  return c.u;  // lo = a, hi = b
}
static __device__ __forceinline__ float ex2(float x) {
#if __has_builtin(__builtin_amdgcn_exp2f)
  return __builtin_amdgcn_exp2f(x);                  // raw v_exp_f32 (2^x)
#else
  return exp2f(x);
#endif
}
static __device__ __forceinline__ float4v fzero() {
  float4v z; z[0] = 0.f; z[1] = 0.f; z[2] = 0.f; z[3] = 0.f; return z;
}
static __device__ __forceinline__ float16v fzero16() {
  float16v z;
#pragma unroll
  for (int i = 0; i < 16; ++i) z[i] = 0.f;
  return z;
}
// v_permlane32_swap_b32 a, b:
//   a <- (a_lo, b_lo)  [b's lower half into a's upper half]
//   b <- (a_hi, b_hi)  [a's upper half into b's lower half]
static __device__ __forceinline__ void pl32swap(unsigned& a, unsigned& b) {
  asm volatile("v_permlane32_swap_b32 %0, %1" : "+v"(a), "+v"(b));
}
// async global->LDS, 16B per lane; LDS dest is wave-uniform base + lane*16
static __device__ __forceinline__ void load_lds16(const void* g, void* l) {
  typedef const __attribute__((address_space(1))) void* gp_t;
  typedef __attribute__((address_space(3))) void* lp_t;
  __builtin_amdgcn_global_load_lds((gp_t)(uintptr_t)g, (lp_t)(uint32_t)(uintptr_t)l, 16, 0, 0);
}

// ---------------------------------------------------------------------------
__global__ void detect_dtype(const unsigned short* __restrict__ x, int* flag) {
  __shared__ int cnt;
  if (threadIdx.x == 0) cnt = 0;
  __syncthreads();
  int c = 0;
  for (int i = threadIdx.x; i < 4096; i += 256) {
    const unsigned v = x[i] & 0x7FFFu;
    if ((v >> 7) >= 134u) ++c;   // exponent >= 134 -> |value| >= 128
  }
  atomicAdd(&cnt, c);
  __syncthreads();
  if (threadIdx.x == 0) *flag = (cnt > 64) ? 1 : 0;
}

// ---------------------------------------------------------------------------
// All 4 input tensors converted (or copied) in one launch; 8 elems/thread.
// ---------------------------------------------------------------------------
static __device__ __forceinline__ void cv8(const void* src, unsigned short* dst,
                                           int i, int fl) {
  if (fl) {
    const float4v a = *(const float4v*)((const float*)src + i);
    const float4v b = *(const float4v*)((const float*)src + i + 4);
    short8 o;
    o[0] = (short)f2bf(a[0]); o[1] = (short)f2bf(a[1]);
    o[2] = (short)f2bf(a[2]); o[3] = (short)f2bf(a[3]);
    o[4] = (short)f2bf(b[0]); o[5] = (short)f2bf(b[1]);
    o[6] = (short)f2bf(b[2]); o[7] = (short)f2bf(b[3]);
    *(short8*)(dst + i) = o;
  } else {
    *(short8*)(dst + i) = *(const short8*)((const unsigned short*)src + i);
  }
}
__global__ __launch_bounds__(256) void convert_all(
    const void* __restrict__ s0, const void* __restrict__ s1,
    const void* __restrict__ s2, const void* __restrict__ s3,
    unsigned short* __restrict__ d0, unsigned short* __restrict__ d1,
    unsigned short* __restrict__ d2, unsigned short* __restrict__ d3,
    const int* __restrict__ flag) {
  const int t = blockIdx.x * 256 + threadIdx.x;
  const int fl = *flag;
  if (t < 1048576)       cv8(s0, d0, t * 8, fl);
  else if (t < 1441792)  cv8(s1, d1, (t - 1048576) * 8, fl);
  else if (t < 1572864)  cv8(s2, d2, (t - 1441792) * 8, fl);
  else if (t < 1572992)  cv8(s3, d3, (t - 1572864) * 8, fl);
}

// ---------------------------------------------------------------------------
// GEMM1: qkv[m,e] = sum_k X[m,k]*Wqkv[e,k];  M=8192, E=3072, K=1024
// 128x128 tile, BK=64 (16 iters), T3-min dbuf, T2 chunk-XOR swizzle:
// LDS[row][c] holds G[row][c^(row&7)] (16B chunks; row stride 128B).
// Store side: pre-swizzled global source, linear gload_lds dest (rule #21).
// Read side: chunk (ks*4+quad)^(l16&7). Q epilogue pre-scales by
// SCALE*log2(e) so flash softmax can use 2^x.
// ---------------------------------------------------------------------------
__global__ __launch_bounds__(256) void qkv_gemm(
    const unsigned short* __restrict__ X, const unsigned short* __restrict__ W,
    unsigned short* __restrict__ Qo, unsigned short* __restrict__ Ko,
    unsigned short* __restrict__ Vt) {
  __shared__ __attribute__((aligned(16))) unsigned short lA[2][128 * 64];
  __shared__ __attribute__((aligned(16))) unsigned short lB[2][128 * 64];
  const int tid = threadIdx.x;
  const int wave = tid >> 6, lane = tid & 63, quad = lane >> 4, l16 = lane & 15;
  const int wm = wave >> 1, wn = wave & 1;
  const int m0 = blockIdx.x * 128, n0 = blockIdx.y * 128;

  float4v acc[4][4];
  for (int i = 0; i < 4; ++i) for (int j = 0; j < 4; ++j) acc[i][j] = fzero();

  // staging: 4 rounds x 2 matrices; round r covers f = r*256+tid,
  // row = f>>3 (32 rows/round), chunk = f&7; source chunk pre-swizzled.
  int srow[4], scol[4];
#pragma unroll
  for (int r = 0; r < 4; ++r) {
    const int f = r * 256 + tid;
    srow[r] = f >> 3;
    scol[r] = ((f & 7) ^ (srow[r] & 7)) * 8;   // elem offset of 16B chunk
  }
  const int lsw = l16 & 7;                      // read-side row swizzle

#define QKV_STAGE(buf, k0)                                                    \
  {                                                                           \
    _Pragma("unroll")                                                         \
    for (int r = 0; r < 4; ++r) {                                             \
      const int dof = (r * 256 + wave * 64) * 8;                              \
      load_lds16(X + (size_t)(m0 + srow[r]) * 1024 + (k0) + scol[r],          \
                 lA[buf] + dof);                                              \
      load_lds16(W + (size_t)(n0 + srow[r]) * 1024 + (k0) + scol[r],          \
                 lB[buf] + dof);                                              \
    }                                                                         \
  }

  QKV_STAGE(0, 0);
  __syncthreads();                // drains prologue loads
  int cur = 0;
  for (int k0 = 0; k0 < 1024; k0 += 64) {
    if (k0 < 960) { QKV_STAGE(cur ^ 1, k0 + 64); }   // next tile in flight
#pragma unroll
    for (int ks = 0; ks < 2; ++ks) {
      short8 af[4], bfr[4];
#pragma unroll
      for (int t = 0; t < 4; ++t) {
        const int rowA = wm * 64 + t * 16 + l16;
        const int rowB = wn * 64 + t * 16 + l16;
        const int ch = ((ks * 4 + quad) ^ lsw) * 8;
        af[t]  = *(const short8*)(lA[cur] + rowA * 64 + ch);
        bfr[t] = *(const short8*)(lB[cur] + rowB * 64 + ch);
      }
#pragma unroll
      for (int mt = 0; mt < 4; ++mt)
#pragma unroll
        for (int nt = 0; nt < 4; ++nt)
          acc[mt][nt] = MFMA16(af[mt], bfr[nt], acc[mt][nt]);
    }
    __syncthreads();              // drains next-tile loads (post-compute)
    cur ^= 1;
  }
#undef QKV_STAGE

  // 0.125 * log2(e) — softmax exponent base folded into Q
  const float QSCALE = 0.18033688011112042f;
  for (int mt = 0; mt < 4; ++mt) {
    const int mbase = m0 + wm * 64 + mt * 16 + quad * 4;
    const int b = mbase >> 11;
    const int nrow = mbase & 2047;
    for (int nt = 0; nt < 4; ++nt) {
      const int e = n0 + wn * 64 + nt * 16 + l16;
      const int c = e >> 10, h = (e >> 6) & 15, hd = e & 63;
      const int bh = b * 16 + h;
      if (c == 0) {        // Q, pre-scaled by 1/8 * log2(e)
        for (int r = 0; r < 4; ++r)
          Qo[((size_t)bh * 2048 + nrow + r) * 64 + hd] = f2bf(acc[mt][nt][r] * QSCALE);
      } else if (c == 1) { // K
        for (int r = 0; r < 4; ++r)
          Ko[((size_t)bh * 2048 + nrow + r) * 64 + hd] = f2bf(acc[mt][nt][r]);
      } else {             // V transposed: Vt[bh][hd][n]
        short4v pk;
        for (int r = 0; r < 4; ++r) pk[r] = (short)f2bf(acc[mt][nt][r]);
        *(short4v*)(Vt + ((size_t)bh * 64 + hd) * 2048 + nrow) = pk;
      }
    }
  }
}

// ---------------------------------------------------------------------------
// Flash attention v5b: block = 128 q x one (b,h); 4 waves x 32 queries each.
// 32x32x16 MFMA for S^T and PV. Double-buffered K/V LDS, T14 async-stage.
// S^T C-regs: query=l31, key=(reg&3)+8*(reg>>2)+4*hi (+32*kb2).
// PV B-frag (element i = key 8*hi+i) built via cvt_pk + permlane32_swap.
// ---------------------------------------------------------------------------
__global__ __launch_bounds__(256, 4) void flash_attn(
    const unsigned short* __restrict__ Q, const unsigned short* __restrict__ K,
    const unsigned short* __restrict__ Vt, unsigned short* __restrict__ AO) {
  __shared__ __attribute__((aligned(16))) unsigned short lK[2][64 * 72];   // (key, hd)
  __shared__ __attribute__((aligned(16))) unsigned short lV[2][64 * 72];   // (hd, key)
  const int tid = threadIdx.x;
  const int wave = tid >> 6, lane = tid & 63;
  const int l31 = lane & 31, hi = lane >> 5;
  const int qt = blockIdx.x, bh = blockIdx.y;
  const int b = bh >> 4, h = bh & 15;
  const size_t base = (size_t)bh * 2048 * 64;
  const unsigned short* Qp = Q + base;
  const unsigned short* Kp = K + base;
  const unsigned short* Vp = Vt + base;
  const int q0 = qt * 128;

  // wave owns queries qa..qa (32 of them via l31)
  const int qa = q0 + wave * 32 + l31;
  short8 qf[4];
#pragma unroll
  for (int j = 0; j < 4; ++j)
    qf[j] = *(const short8*)(Qp + (size_t)qa * 64 + j * 16 + hi * 8);

  // O^T accumulators, 2 hd-tiles of 32: col=query=l31, row=hd mapping
  float16v oacc0 = fzero16(), oacc1 = fzero16();
  float lsum = 0.f;   // per-lane partial row sum for query l31 (half keys)

  const int f0 = tid, f1 = 256 + tid;
  const int sk0 = (f0 >> 3) * 72 + (f0 & 7) * 8;   // padded LDS elem offset
  const int sk1 = (f1 >> 3) * 72 + (f1 & 7) * 8;

  // prologue: tile 0 into staging registers
  short8 kv0 = *(const short8*)(Kp + f0 * 8);
  short8 kv1 = *(const short8*)(Kp + f1 * 8);
  short8 vv0 = *(const short8*)(Vp + (size_t)(f0 >> 3) * 2048 + (f0 & 7) * 8);
  short8 vv1 = *(const short8*)(Vp + (size_t)(f1 >> 3) * 2048 + (f1 & 7) * 8);

  for (int kb = 0; kb < 32; ++kb) {
    unsigned short* const Kb = lK[kb & 1];
    unsigned short* const Vb = lV[kb & 1];
    // write staged tile (auto vmcnt wait lands here — loads had a full
    // compute phase to return)
    *(short8*)(Kb + sk0) = kv0;
    *(short8*)(Kb + sk1) = kv1;
    *(short8*)(Vb + sk0) = vv0;
    *(short8*)(Vb + sk1) = vv1;
    __syncthreads();
    // T14: issue next-tile loads AFTER the barrier so its vmcnt(0) drain
    // doesn't intercept them; latency hides under S^T/exp/PV below.
    if (kb < 31) {
      const size_t ko = (size_t)(kb + 1) * 4096;
      kv0 = *(const short8*)(Kp + ko + f0 * 8);
      kv1 = *(const short8*)(Kp + ko + f1 * 8);
      vv0 = *(const short8*)(Vp + (size_t)(f0 >> 3) * 2048 + (kb + 1) * 64 + (f0 & 7) * 8);
      vv1 = *(const short8*)(Vp + (size_t)(f1 >> 3) * 2048 + (kb + 1) * 64 + (f1 & 7) * 8);
    }

#pragma unroll
    for (int kb2 = 0; kb2 < 2; ++kb2) {
      // S^T = K Q^T (32 keys x 32 queries): A = K-frag row=key=l31,
      // k = j*16 + hi*8 + i; B = Q-frag col=query=l31, same k.
      const unsigned short* krow = Kb + (kb2 * 32 + l31) * 72 + hi * 8;
      float16v s = fzero16();
#pragma unroll
      for (int j = 0; j < 4; ++j)
        s = MFMA32(*(const short8*)(krow + j * 16), qf[j], s);

      // 2^s; lane holds keys (reg&3)+8*(reg>>2)+4*hi for reg 0..15
      unsigned u[8];
      float ls = 0.f;
#pragma unroll
      for (int j = 0; j < 8; ++j) {
        const float e0 = ex2(s[2 * j]);
        const float e1 = ex2(s[2 * j + 1]);
        ls += e0 + e1;
        u[j] = pkbf(e0, e1);
      }
      lsum += ls;

      // Relayout to PV B-frags (element i = key 8*hi+i):
      //   swap(u0,u2): u0 <- (u0_lo|u2_lo) = keys (0,1)|(8,9)   = w0
      //                u2 <- (u0_hi|u2_hi) = keys (4,5)|(12,13) = w2
      pl32swap(u[0], u[2]); pl32swap(u[1], u[3]);   // keys 0..15
      pl32swap(u[4], u[6]); pl32swap(u[5], u[7]);   // keys 16..31
      union { unsigned w[4]; short8 s8; } fr0, fr1;
      fr0.w[0] = u[0]; fr0.w[1] = u[1]; fr0.w[2] = u[2]; fr0.w[3] = u[3];
      fr1.w[0] = u[4]; fr1.w[1] = u[5]; fr1.w[2] = u[6]; fr1.w[3] = u[7];

      // O^T += V^T P^T: A = V^T row=hd=l31(+32), k=key=kb2*32+s*16+8*hi+i
      const unsigned short* vrow0 = Vb + l31 * 72 + kb2 * 32 + hi * 8;
      const unsigned short* vrow1 = vrow0 + 32 * 72;
      oacc0 = MFMA32(*(const short8*)(vrow0), fr0.s8, oacc0);
      oacc1 = MFMA32(*(const short8*)(vrow1), fr0.s8, oacc1);
      oacc0 = MFMA32(*(const short8*)(vrow0 + 16), fr1.s8, oacc0);
      oacc1 = MFMA32(*(const short8*)(vrow1 + 16), fr1.s8, oacc1);
    }
  }

  // row-sum: each lane has half the keys for query l31; combine hi-halves
  lsum += __shfl_xor(lsum, 32);
  const float inv = 1.f / lsum;

  // AO[b][query][h*64+hd]; hd = mt*32 + 8*g + 4*hi + r (regs 4g..4g+3)
  unsigned short* ao = AO + ((size_t)(b * 2048 + qa)) * 1024 + h * 64 + hi * 4;
#pragma unroll
  for (int mt = 0; mt < 2; ++mt) {
    const float16v& oc = mt ? oacc1 : oacc0;
#pragma unroll
    for (int g = 0; g < 4; ++g) {
      union { unsigned u2[2]; short4v s4; } o;
      o.u2[0] = pkbf(oc[4 * g] * inv, oc[4 * g + 1] * inv);
      o.u2[1] = pkbf(oc[4 * g + 2] * inv, oc[4 * g + 3] * inv);
      *(short4v*)(ao + mt * 32 + g * 8) = o.s4;
    }
  }
}

// ---------------------------------------------------------------------------
// GEMM2: out[m,e] = sum_k A[m,k]*Wp[e,k] + bias[e]; BK=64 + T2 swizzle
// (same structure as qkv_gemm); adaptive out dtype.
// ---------------------------------------------------------------------------
__global__ __launch_bounds__(256) void proj_gemm(
    const unsigned short* __restrict__ A, const unsigned short* __restrict__ W,
    const unsigned short* __restrict__ bias_bf, const void* __restrict__ bias_raw,
    void* __restrict__ outv, const int* __restrict__ flag) {
  __shared__ __attribute__((aligned(16))) unsigned short lA[2][128 * 64];
  __shared__ __attribute__((aligned(16))) unsigned short lB[2][128 * 64];
  const int tid = threadIdx.x;
  const int wave = tid >> 6, lane = tid & 63, quad = lane >> 4, l16 = lane & 15;
  const int wm = wave >> 1, wn = wave & 1;
  const int m0 = blockIdx.x * 128, n0 = blockIdx.y * 128;
  const int fl = *flag;

  float4v acc[4][4];
  for (int i = 0; i < 4; ++i) for (int j = 0; j < 4; ++j) acc[i][j] = fzero();

  int srow[4], scol[4];
#pragma unroll
  for (int r = 0; r < 4; ++r) {
    const int f = r * 256 + tid;
    srow[r] = f >> 3;
    scol[r] = ((f & 7) ^ (srow[r] & 7)) * 8;
  }
  const int lsw = l16 & 7;

#define PROJ_STAGE(buf, k0)                                                   \
  {                                                                           \
    _Pragma("unroll")                                                         \
    for (int r = 0; r < 4; ++r) {                                             \
      const int dof = (r * 256 + wave * 64) * 8;                              \
      load_lds16(A + (size_t)(m0 + srow[r]) * 1024 + (k0) + scol[r],          \
                 lA[buf] + dof);                                              \
      load_lds16(W + (size_t)(n0 + srow[r]) * 1024 + (k0) + scol[r],          \
                 lB[buf] + dof);                                              \
    }                                                                         \
  }

  PROJ_STAGE(0, 0);
  __syncthreads();
  int cur = 0;
  for (int k0 = 0; k0 < 1024; k0 += 64) {
    if (k0 < 960) { PROJ_STAGE(cur ^ 1, k0 + 64); }
#pragma unroll
    for (int ks = 0; ks < 2; ++ks) {
      short8 af[4], bfr[4];
#pragma unroll
      for (int t = 0; t < 4; ++t) {
        const int rowA = wm * 64 + t * 16 + l16;
        const int rowB = wn * 64 + t * 16 + l16;
        const int ch = ((ks * 4 + quad) ^ lsw) * 8;
        af[t]  = *(const short8*)(lA[cur] + rowA * 64 + ch);
        bfr[t] = *(const short8*)(lB[cur] + rowB * 64 + ch);
      }
#pragma unroll
      for (int mt = 0; mt < 4; ++mt)
#pragma unroll
        for (int nt = 0; nt < 4; ++nt)
          acc[mt][nt] = MFMA16(af[mt], bfr[nt], acc[mt][nt]);
    }
    __syncthreads();
    cur ^= 1;
  }
#undef PROJ_STAGE

  for (int mt = 0; mt < 4; ++mt) {
    const int mbase = m0 + wm * 64 + mt * 16 + quad * 4;
    for (int nt = 0; nt < 4; ++nt) {
      const int e = n0 + wn * 64 + nt * 16 + l16;
      const float bv = fl ? ((const float*)bias_raw)[e] : bf2f(bias_bf[e]);
      for (int r = 0; r < 4; ++r) {
        const float val = acc[mt][nt][r] + bv;
        const size_t idx = (size_t)(mbase + r) * 1024 + e;
        if (fl) ((float*)outv)[idx] = val;
        else    ((unsigned short*)outv)[idx] = f2bf(val);
      }
    }
  }
}

// ---------------------------------------------------------------------------
extern "C" void kernel_launch(void* const* d_in, const int* in_sizes, int n_in,
                              void* d_out, int out_size, void* d_ws, size_t ws_size,
                              hipStream_t stream) {
  const void* x_raw     = d_in[0];  // (8192,1024)
  const void* wqkv_raw  = d_in[1];  // (3072,1024)
  const void* wproj_raw = d_in[2];  // (1024,1024)
  const void* bproj_raw = d_in[3];  // (1024,)

  const size_t NE = (size_t)4 * 16 * 2048 * 64;  // 8388608
  unsigned short* ws = (unsigned short*)d_ws;
  unsigned short* Q      = ws;
  unsigned short* K      = Q + NE;
  unsigned short* Vt     = K + NE;
  unsigned short* xb     = Vt + NE;        // also AO (xb dead after qkv_gemm)
  unsigned short* AO     = xb;
  unsigned short* wqkvb  = xb + NE;
  unsigned short* wprojb = wqkvb + 3145728;
  unsigned short* bprojb = wprojb + 1048576;
  int* flag = (int*)(bprojb + 1024);

  detect_dtype<<<1, 256, 0, stream>>>((const unsigned short*)x_raw, flag);
  convert_all<<<6145, 256, 0, stream>>>(x_raw, wqkv_raw, wproj_raw, bproj_raw,
                                        xb, wqkvb, wprojb, bprojb, flag);

  qkv_gemm<<<dim3(64, 24), 256, 0, stream>>>(xb, wqkvb, Q, K, Vt);
  flash_attn<<<dim3(16, 64), 256, 0, stream>>>(Q, K, Vt, AO);
  proj_gemm<<<dim3(64, 8), 256, 0, stream>>>(AO, wprojb, bprojb, bproj_raw,
                                             d_out, flag);
}